// Round 1
// baseline (97.658 us; speedup 1.0000x reference)
//
#include <hip/hip_runtime.h>

#define BIG 1e9f

// One 64-lane wave per batch sample. Lane j owns column j of the 64x64 grid.
// Row recurrence v[j] = min(c[j], v[j-1] + a[j]) solved by an associative
// scan over pairs (a, c): combine((a1,c1),(a2,c2)) = (a1+a2, min(c2, c1+a2)).
__global__ __launch_bounds__(256) void dp_path_kernel(const float* __restrict__ img,
                                                      float* __restrict__ out,
                                                      int B) {
    const int gtid = blockIdx.x * blockDim.x + threadIdx.x;
    const int b = gtid >> 6;          // wave index = batch sample
    const int lane = threadIdx.x & 63;
    if (b >= B) return;

    const float* p = img + (size_t)b * 64 * 64;

    // ---- Row 0: c = (0, BIG, ...), a = (BIG, t_right...) -> scan == cumsum ----
    float x   = p[lane];              // img[0][lane]
    float xm1 = __shfl_up(x, 1);      // img[0][lane-1]
    float a = (lane >= 1) ? 0.5f * (xm1 + x) : BIG;
    float c = (lane == 0) ? 0.0f : BIG;

    #pragma unroll
    for (int off = 1; off < 64; off <<= 1) {
        float a_up = __shfl_up(a, off);
        float c_up = __shfl_up(c, off);
        if (lane >= off) {
            c = fminf(c, c_up + a);   // uses pre-update a (= a_y)
            a += a_up;
        }
    }
    float v = c;          // d[0][j]
    float xprev    = x;   // img[i-1][lane]
    float xprev_m1 = xm1; // img[i-1][lane-1]

    // ---- Rows 1..63 ----
    for (int i = 1; i < 64; ++i) {
        x   = p[i * 64 + lane];       // img[i][lane]   (coalesced)
        xm1 = __shfl_up(x, 1);        // img[i][lane-1]
        float v_m1 = __shfl_up(v, 1); // d[i-1][lane-1]

        // candidates entering the row: down edge, then diag edge
        c = v + 0.5f * (xprev + x);
        if (lane >= 1) {
            c = fminf(c, v_m1 + 0.5f * (xprev_m1 + x));
        }
        a = (lane >= 1) ? 0.5f * (xm1 + x) : BIG;

        // min-plus scan folds in the right edges within the row
        #pragma unroll
        for (int off = 1; off < 64; off <<= 1) {
            float a_up = __shfl_up(a, off);
            float c_up = __shfl_up(c, off);
            if (lane >= off) {
                c = fminf(c, c_up + a);
                a += a_up;
            }
        }
        v = c;
        xprev    = x;
        xprev_m1 = xm1;
    }

    if (lane == 63) out[b] = v;       // d[63][63]
}

extern "C" void kernel_launch(void* const* d_in, const int* in_sizes, int n_in,
                              void* d_out, int out_size, void* d_ws, size_t ws_size,
                              hipStream_t stream) {
    const float* img = (const float*)d_in[0];
    float* out = (float*)d_out;
    const int B = out_size;                 // 2048 samples
    const int threads = 256;                // 4 waves per block
    const int waves_per_block = threads / 64;
    const int grid = (B + waves_per_block - 1) / waves_per_block;
    dp_path_kernel<<<grid, threads, 0, stream>>>(img, out, B);
}

// Round 2
// 74.728 us; speedup vs baseline: 1.3069x; 1.3069x over previous
//
#include <hip/hip_runtime.h>

#define BIG 1e9f

// wave_shr:1 via DPP: lane j gets src from lane j-1; lane 0 gets `old_v`.
// Single VALU instruction (v_mov_b32_dpp), no LDS pipe, ~5 cyc dependent latency.
__device__ __forceinline__ float dpp_shr1(float src, float old_v) {
    return __int_as_float(__builtin_amdgcn_update_dpp(
        __float_as_int(old_v), __float_as_int(src),
        0x138 /* wave_shr:1 */, 0xF, 0xF, false));
}

// One 64-lane wave per sample; lane j owns column j.
// Anti-diagonal sweep: diagonal k holds cells (i=k-j, j). Recurrence:
//   d[i][j] = 0.5*img[i][j] + min( d[i][j-1]   + 0.5*img[i][j-1],
//                                  d[i-1][j]   + 0.5*img[i-1][j],
//                                  d[i-1][j-1] + 0.5*img[i-1][j-1] )
// All neighbor terms are lane j / lane j-1 values from diagonals k-1, k-2,
// carried in registers; cross-lane via wave_shr:1. Inactive lanes ride at
// ~BIG and are excluded by min (lane activates at k=j reading only valid
// lane j-1 data; lane j goes stale only after its consumer is done).
__global__ __launch_bounds__(128) void dp_diag_kernel(const float* __restrict__ img,
                                                      float* __restrict__ out, int B) {
    __shared__ float smem[2][4096];   // 16 KB per wave
    const int lane = threadIdx.x & 63;
    const int wave = threadIdx.x >> 6;
    const int b = (blockIdx.x << 1) + wave;
    const bool active = (b < B);

    float* s = smem[wave];
    if (active) {
        // coalesced float4 stage: 16 iters x 64 lanes x 16B = 16 KB
        const float4* g4 = (const float4*)(img + ((size_t)b << 12));
        float4* s4 = (float4*)s;
        #pragma unroll
        for (int t = 0; t < 16; ++t)
            s4[(t << 6) + lane] = g4[(t << 6) + lane];
    }
    __syncthreads();   // unguarded: avoids barrier divergence if B odd

    if (active) {
        // k = 0 state: cell (0,0) = 0, everything else BIG.
        float d_prev = (lane == 0) ? 0.0f : BIG;  // d on diag k-1 (lane j)
        float d_pp   = BIG;                       // d on diag k-2 (lane j)
        // h = 0.5*img[i][j]; at k=0 (i clamped to 0) => 0.5*img[0][j],
        // which is exactly what row-0 activation needs.
        float h_prev   = 0.5f * s[lane];
        float hm1_prev = 0.0f;   // only feeds c3 vs BIG at k=1 -> irrelevant

        #pragma unroll 14
        for (int k = 1; k <= 126; ++k) {
            int i  = k - lane;
            int ic = i < 0 ? 0 : (i > 63 ? 63 : i);          // v_med3_i32
            float x = s[(ic << 6) + lane];                   // bank j%32: conflict-free
            float h = 0.5f * x;

            float hm1   = dpp_shr1(h_prev, 0.0f);   // 0.5*img[i][j-1]
            float shd   = dpp_shr1(d_prev, BIG);    // d[i][j-1]
            float shdpp = dpp_shr1(d_pp,   BIG);    // d[i-1][j-1]

            float c1 = shd   + hm1;        // via right edge
            float c2 = d_prev + h_prev;    // via down edge
            float c3 = shdpp + hm1_prev;   // via diag edge
            float d  = fminf(fminf(c1, c2), c3) + h;

            d_pp     = d_prev;
            d_prev   = d;
            hm1_prev = hm1;
            h_prev   = h;
        }
        if (lane == 63) out[b] = d_prev;   // d[63][63] lives on diag 126, lane 63
    }
}

extern "C" void kernel_launch(void* const* d_in, const int* in_sizes, int n_in,
                              void* d_out, int out_size, void* d_ws, size_t ws_size,
                              hipStream_t stream) {
    const float* img = (const float*)d_in[0];
    float* out = (float*)d_out;
    const int B = out_size;                  // 2048
    const int threads = 128;                 // 2 waves (samples) per block
    const int grid = (B + 1) / 2;
    dp_diag_kernel<<<grid, threads, 0, stream>>>(img, out, B);
}